// Round 1
// baseline (1280.565 us; speedup 1.0000x reference)
//
#include <hip/hip_runtime.h>

#define NEG (-1e30f)

constexpr int Bn = 16;
constexpr int Tn = 512;
constexpr int Dn = 256;
constexpr int Vn = 4233;
constexpr int Ln = 64;    // LMAX
constexpr int Sn = 129;   // 2*LMAX+1
constexpr int SP = 132;   // padded stride for lp_ext rows

__device__ __forceinline__ float lae2(float x, float y) {
    float m = fmaxf(x, y);
    return m + __logf(__expf(x - m) + __expf(y - m));
}

__device__ __forceinline__ float lae3(float x, float y, float z) {
    float m = fmaxf(fmaxf(x, y), z);
    return m + __logf(__expf(x - m) + __expf(y - m) + __expf(z - m));
}

// Kernel A: for each (b,t) row, compute lse = log(sum_v exp(logit)) and the
// 129 gathered log-probs lp_ext[b,t,s] = logit(ext[b,s]) - lse.
// One block handles 8 consecutive rows (same b since 8 | 512).
__global__ __launch_bounds__(256) void proj_lse_gather(
    const float* __restrict__ hs, const int* __restrict__ ys,
    const float* __restrict__ W, const float* __restrict__ bias,
    float* __restrict__ lp)
{
    __shared__ __align__(16) float sh_hs[8][Dn];
    __shared__ float red[4][8];
    __shared__ float sh_lse[8];
    __shared__ float sh_lp[8][65];

    const int tid  = threadIdx.x;
    const int n0   = blockIdx.x * 8;       // global row index base (b*T + t)
    const int b    = n0 >> 9;              // n0 / T
    const int lane = tid & 63;
    const int wave = tid >> 6;

    const float* hrow = hs + (size_t)n0 * Dn;

    // stage hs tile for phase 2 (per-lane row access there)
    #pragma unroll
    for (int r = 0; r < 8; ++r) sh_hs[r][tid] = hrow[r * Dn + tid];
    __syncthreads();

    // ---- phase 1: sum of exp(logit) over all V, 4 vocab x 8 rows per thread ----
    const float4* hrow4 = (const float4*)hrow;   // block-uniform addresses

    float se[8];
    #pragma unroll
    for (int r = 0; r < 8; ++r) se[r] = 0.0f;

    for (int i = 0; i < 5; ++i) {
        int v0 = i * 1024 + tid;
        int   vc[4];
        bool  valid[4];
        const float4* wr[4];
        #pragma unroll
        for (int j = 0; j < 4; ++j) {
            int v = v0 + 256 * j;
            valid[j] = (v < Vn);
            vc[j] = valid[j] ? v : (Vn - 1);
            wr[j] = (const float4*)(W + (size_t)vc[j] * Dn);
        }

        float acc[4][8];
        #pragma unroll
        for (int j = 0; j < 4; ++j)
            #pragma unroll
            for (int r = 0; r < 8; ++r) acc[j][r] = 0.0f;

        for (int d4 = 0; d4 < Dn / 4; ++d4) {
            float4 w[4];
            #pragma unroll
            for (int j = 0; j < 4; ++j) w[j] = wr[j][d4];
            #pragma unroll
            for (int r = 0; r < 8; ++r) {
                float4 h = hrow4[r * (Dn / 4) + d4];   // uniform -> scalar loads
                #pragma unroll
                for (int j = 0; j < 4; ++j) {
                    acc[j][r] = fmaf(h.x, w[j].x, acc[j][r]);
                    acc[j][r] = fmaf(h.y, w[j].y, acc[j][r]);
                    acc[j][r] = fmaf(h.z, w[j].z, acc[j][r]);
                    acc[j][r] = fmaf(h.w, w[j].w, acc[j][r]);
                }
            }
        }

        #pragma unroll
        for (int j = 0; j < 4; ++j) {
            float bb = bias[vc[j]];
            #pragma unroll
            for (int r = 0; r < 8; ++r) {
                float lg = valid[j] ? (acc[j][r] + bb) : NEG;
                se[r] += __expf(lg);
            }
        }
    }

    // block reduction of se per row
    #pragma unroll
    for (int r = 0; r < 8; ++r) {
        float v = se[r];
        #pragma unroll
        for (int off = 32; off > 0; off >>= 1) v += __shfl_xor(v, off, 64);
        if (lane == 0) red[wave][r] = v;
    }
    __syncthreads();
    if (tid < 8)
        sh_lse[tid] = __logf(red[0][tid] + red[1][tid] + red[2][tid] + red[3][tid]);
    __syncthreads();

    // ---- phase 2a: 65 unique label dots per row (u=0 -> blank) ----
    for (int task = tid; task < 8 * 65; task += 256) {
        int r = task / 65;
        int u = task - r * 65;
        int v = (u == 0) ? 0 : ys[b * Ln + (u - 1)];
        const float4* wrow = (const float4*)(W + (size_t)v * Dn);
        const float4* hr   = (const float4*)(&sh_hs[r][0]);
        float acc = 0.0f;
        for (int d4 = 0; d4 < Dn / 4; ++d4) {
            float4 w = wrow[d4];
            float4 h = hr[d4];
            acc = fmaf(h.x, w.x, acc);
            acc = fmaf(h.y, w.y, acc);
            acc = fmaf(h.z, w.z, acc);
            acc = fmaf(h.w, w.w, acc);
        }
        sh_lp[r][u] = acc + bias[v] - sh_lse[r];
    }
    __syncthreads();

    // ---- phase 2b: scatter to the padded [n][SP] lp_ext buffer ----
    for (int idx = tid; idx < 8 * Sn; idx += 256) {
        int r = idx / Sn;
        int s = idx - r * Sn;
        int u = (s & 1) ? ((s >> 1) + 1) : 0;
        lp[(size_t)(n0 + r) * SP + s] = sh_lp[r][u];
    }
}

// Kernel B: CTC forward recursion. One wave per batch element.
// Lane l holds alpha[2l] (a0), alpha[2l+1] (a1); lane 63 also alpha[128] (a2).
__global__ __launch_bounds__(64) void ctc_fwd(
    const float* __restrict__ lp, const int* __restrict__ ys,
    const int* __restrict__ hlens, const int* __restrict__ ylens,
    float* __restrict__ ll_out)
{
    const int b = blockIdx.x;
    const int l = threadIdx.x;

    int yl  = ys[b * Ln + l];
    int ylm = (l >= 1) ? ys[b * Ln + l - 1] : -1;
    const bool allow1 = (l >= 1) && (yl != ylm);   // s = 2l+1, s-2 path
    const int hl = hlens[b];

    const float* lpb = lp + (size_t)b * Tn * SP;

    float a0 = NEG, a1 = NEG, a2 = NEG;
    {
        float2 c = *(const float2*)(lpb + 2 * l);
        if (l == 0) { a0 = c.x; a1 = c.y; }
    }

    // prefetch t=1
    float2 c01  = *(const float2*)(lpb + SP + 2 * l);
    float  c128 = lpb[SP + 128];

    for (int t = 1; t < Tn; ++t) {
        int tn = (t + 1 < Tn) ? (t + 1) : t;
        float2 n01  = *(const float2*)(lpb + (size_t)tn * SP + 2 * l);
        float  n128 = lpb[(size_t)tn * SP + 128];

        float p1 = __shfl_up(a1, 1, 64);   // alpha[2l-1] from lane l-1
        if (l == 0) p1 = NEG;

        float u0 = lae2(a0, p1) + c01.x;                         // even s: no s-2 path
        float u1 = lae3(a1, a0, allow1 ? p1 : NEG) + c01.y;      // odd s
        float u2 = lae2(a2, a1) + c128;                          // s=128 (lane 63)

        bool act = (t < hl);
        a0 = act ? u0 : a0;
        a1 = act ? u1 : a1;
        a2 = act ? u2 : a2;

        c01 = n01; c128 = n128;
    }

    __shared__ float sh[132];
    sh[2 * l]     = a0;
    sh[2 * l + 1] = a1;
    if (l == 63) sh[128] = a2;
    __syncthreads();

    if (l == 0) {
        int L = ylens[b];
        float ll = lae2(sh[2 * L], sh[2 * L - 1]);
        ll_out[b] = ll;
    }
}

__global__ void finalize(const float* __restrict__ ll, float* __restrict__ out) {
    if (threadIdx.x == 0 && blockIdx.x == 0) {
        float s = 0.0f;
        #pragma unroll
        for (int b = 0; b < Bn; ++b) s += ll[b];
        out[0] = -s / (float)Bn;
    }
}

extern "C" void kernel_launch(void* const* d_in, const int* in_sizes, int n_in,
                              void* d_out, int out_size, void* d_ws, size_t ws_size,
                              hipStream_t stream) {
    const float* hs    = (const float*)d_in[0];
    const int*   hlens = (const int*)d_in[1];
    const int*   ys    = (const int*)d_in[2];
    const int*   ylens = (const int*)d_in[3];
    const float* W     = (const float*)d_in[4];
    const float* bias  = (const float*)d_in[5];
    float* out = (float*)d_out;

    float* lp = (float*)d_ws;                       // [B*T][SP]
    float* ll = lp + (size_t)Bn * Tn * SP;          // [B]

    proj_lse_gather<<<(Bn * Tn) / 8, 256, 0, stream>>>(hs, ys, W, bias, lp);
    ctc_fwd<<<Bn, 64, 0, stream>>>(lp, ys, hlens, ylens, ll);
    finalize<<<1, 64, 0, stream>>>(ll, out);
}

// Round 2
// 415.097 us; speedup vs baseline: 3.0850x; 3.0850x over previous
//
#include <hip/hip_runtime.h>

#define NEG (-1e30f)

constexpr int Bn = 16;
constexpr int Tn = 512;
constexpr int Dn = 256;
constexpr int Vn = 4233;
constexpr int Vp = 4288;   // V padded to 67*64
constexpr int Ln = 64;     // LMAX
constexpr int Un = 80;     // padded gathered-label count (65 -> 80 = 5*16)
constexpr int LP = 72;     // LDS row stride in bf16 (64 + 8 pad)

typedef __attribute__((ext_vector_type(8))) short short8;
typedef __attribute__((ext_vector_type(4))) float f32x4;

__device__ __forceinline__ float lae2(float x, float y) {
    float m = fmaxf(x, y);
    return m + __logf(__expf(x - m) + __expf(y - m));
}
__device__ __forceinline__ float lae3(float x, float y, float z) {
    float m = fmaxf(fmaxf(x, y), z);
    return m + __logf(__expf(x - m) + __expf(y - m) + __expf(z - m));
}

__device__ __forceinline__ unsigned short cvt_bf16(float f) {
    unsigned int u = __float_as_uint(f);
    u = (u + 0x7fffu + ((u >> 16) & 1u)) >> 16;
    return (unsigned short)u;
}

// ---------------- conversion / gather prep ----------------
__global__ __launch_bounds__(256) void conv(
    const float* __restrict__ hs, const float* __restrict__ W,
    const float* __restrict__ bias, const int* __restrict__ ys,
    unsigned short* __restrict__ hs_b, unsigned short* __restrict__ w_b,
    unsigned short* __restrict__ wg_b, float* __restrict__ gbias)
{
    const int gid = blockIdx.x * 256 + threadIdx.x;
    const int stride = gridDim.x * 256;
    const float4* hs4 = (const float4*)hs;
    const float4* W4  = (const float4*)W;

    // hs: 8192*256 floats = 524288 float4
    for (int i = gid; i < (Bn * Tn * Dn) / 4; i += stride) {
        float4 v = hs4[i];
        ushort4 o = make_ushort4(cvt_bf16(v.x), cvt_bf16(v.y), cvt_bf16(v.z), cvt_bf16(v.w));
        *(ushort4*)(&hs_b[i * 4]) = o;
    }
    // W padded: 4288*64 float4
    for (int i = gid; i < Vp * (Dn / 4); i += stride) {
        int row = i >> 6;
        float4 v = make_float4(0.f, 0.f, 0.f, 0.f);
        if (row < Vn) v = W4[i];
        ushort4 o = make_ushort4(cvt_bf16(v.x), cvt_bf16(v.y), cvt_bf16(v.z), cvt_bf16(v.w));
        *(ushort4*)(&w_b[i * 4]) = o;
    }
    // gathered label rows: 16*80*64 float4
    for (int i = gid; i < Bn * Un * (Dn / 4); i += stride) {
        int b = i / (Un * (Dn / 4));
        int rem = i - b * (Un * (Dn / 4));
        int u = rem >> 6;
        int k4 = rem & 63;
        int v = (u == 0) ? 0 : ((u <= Ln) ? ys[b * Ln + u - 1] : -1);
        float4 val = make_float4(0.f, 0.f, 0.f, 0.f);
        if (v >= 0) val = W4[(size_t)v * (Dn / 4) + k4];
        ushort4 o = make_ushort4(cvt_bf16(val.x), cvt_bf16(val.y), cvt_bf16(val.z), cvt_bf16(val.w));
        *(ushort4*)(&wg_b[i * 4]) = o;
    }
    // gathered bias: 16*80
    for (int i = gid; i < Bn * Un; i += stride) {
        int b = i / Un;
        int u = i - b * Un;
        int v = (u == 0) ? 0 : ((u <= Ln) ? ys[b * Ln + u - 1] : -1);
        gbias[i] = (v >= 0) ? bias[v] : 0.0f;
    }
}

// ---------------- main GEMM: sum of exp over V ----------------
// block tile 128 rows x 64 vocab, K staged 64 at a time. 4 waves, each 32x64.
__global__ __launch_bounds__(256) void gemm_se(
    const unsigned short* __restrict__ hs_b, const unsigned short* __restrict__ w_b,
    const float* __restrict__ bias, float* __restrict__ se)
{
    __shared__ short lsA[128 * LP];
    __shared__ short lsB[64 * LP];

    const int tid = threadIdx.x;
    const int lane = tid & 63;
    const int w = tid >> 6;
    const int lr = lane & 15;
    const int kq = lane >> 4;
    const int m0 = blockIdx.x * 128;
    const int n0 = blockIdx.y * 64;
    const int mw = w * 32;

    f32x4 acc[2][4];
    #pragma unroll
    for (int mf = 0; mf < 2; ++mf)
        #pragma unroll
        for (int nf = 0; nf < 4; ++nf)
            acc[mf][nf] = (f32x4){0.f, 0.f, 0.f, 0.f};

    for (int ks = 0; ks < 4; ++ks) {
        const int k0 = ks * 64;
        // stage: A 1024 chunks of 8 bf16, B 512 chunks
        float4 ga[4], gb2[2];
        #pragma unroll
        for (int j = 0; j < 4; ++j) {
            int ch = tid + 256 * j;
            int row = ch >> 3, off = (ch & 7) * 8;
            ga[j] = *(const float4*)(hs_b + (size_t)(m0 + row) * Dn + k0 + off);
        }
        #pragma unroll
        for (int j = 0; j < 2; ++j) {
            int ch = tid + 256 * j;
            int row = ch >> 3, off = (ch & 7) * 8;
            gb2[j] = *(const float4*)(w_b + (size_t)(n0 + row) * Dn + k0 + off);
        }
        __syncthreads();
        #pragma unroll
        for (int j = 0; j < 4; ++j) {
            int ch = tid + 256 * j;
            int row = ch >> 3, off = (ch & 7) * 8;
            *(float4*)(&lsA[row * LP + off]) = ga[j];
        }
        #pragma unroll
        for (int j = 0; j < 2; ++j) {
            int ch = tid + 256 * j;
            int row = ch >> 3, off = (ch & 7) * 8;
            *(float4*)(&lsB[row * LP + off]) = gb2[j];
        }
        __syncthreads();

        #pragma unroll
        for (int sub = 0; sub < 2; ++sub) {
            short8 af[2], bf[4];
            #pragma unroll
            for (int mf = 0; mf < 2; ++mf)
                af[mf] = *(const short8*)(&lsA[(mw + mf * 16 + lr) * LP + sub * 32 + kq * 8]);
            #pragma unroll
            for (int nf = 0; nf < 4; ++nf)
                bf[nf] = *(const short8*)(&lsB[(nf * 16 + lr) * LP + sub * 32 + kq * 8]);
            #pragma unroll
            for (int mf = 0; mf < 2; ++mf)
                #pragma unroll
                for (int nf = 0; nf < 4; ++nf)
                    acc[mf][nf] = __builtin_amdgcn_mfma_f32_16x16x32_bf16(
                        af[mf], bf[nf], acc[mf][nf], 0, 0, 0);
        }
    }

    // epilogue: se[row] += sum over this block's 64 vocab cols of exp(logit)
    float bcol[4]; bool valid[4];
    #pragma unroll
    for (int nf = 0; nf < 4; ++nf) {
        int col = n0 + nf * 16 + lr;
        valid[nf] = (col < Vn);
        bcol[nf] = valid[nf] ? bias[col] : 0.0f;
    }
    #pragma unroll
    for (int mf = 0; mf < 2; ++mf) {
        #pragma unroll
        for (int r = 0; r < 4; ++r) {
            float s = 0.0f;
            #pragma unroll
            for (int nf = 0; nf < 4; ++nf)
                if (valid[nf]) s += __expf(acc[mf][nf][r] + bcol[nf]);
            #pragma unroll
            for (int off = 1; off < 16; off <<= 1) s += __shfl_xor(s, off, 64);
            if (lr == 0)
                atomicAdd(&se[m0 + mw + mf * 16 + kq * 4 + r], s);
        }
    }
}

// ---------------- gathered-label GEMM: raw logits at extended labels ----------------
// per batch: M=512 (4 tiles of 128), N=80. glp[b][t][u] = logit + bias.
__global__ __launch_bounds__(256) void gemm_gather(
    const unsigned short* __restrict__ hs_b, const unsigned short* __restrict__ wg_b,
    const float* __restrict__ gbias, float* __restrict__ glp)
{
    __shared__ short lsA[128 * LP];
    __shared__ short lsB[Un * LP];

    const int tid = threadIdx.x;
    const int lane = tid & 63;
    const int w = tid >> 6;
    const int lr = lane & 15;
    const int kq = lane >> 4;
    const int m0 = blockIdx.x * 128;     // t offset within batch
    const int b = blockIdx.y;
    const int mw = w * 32;

    f32x4 acc[2][5];
    #pragma unroll
    for (int mf = 0; mf < 2; ++mf)
        #pragma unroll
        for (int nf = 0; nf < 5; ++nf)
            acc[mf][nf] = (f32x4){0.f, 0.f, 0.f, 0.f};

    for (int ks = 0; ks < 4; ++ks) {
        const int k0 = ks * 64;
        float4 ga[4];
        #pragma unroll
        for (int j = 0; j < 4; ++j) {
            int ch = tid + 256 * j;
            int row = ch >> 3, off = (ch & 7) * 8;
            ga[j] = *(const float4*)(hs_b + (size_t)(b * Tn + m0 + row) * Dn + k0 + off);
        }
        float4 gbv[3];
        int nb = 0;
        for (int ch = tid; ch < Un * 8; ch += 256, ++nb) {
            int row = ch >> 3, off = (ch & 7) * 8;
            gbv[nb] = *(const float4*)(wg_b + (size_t)(b * Un + row) * Dn + k0 + off);
        }
        __syncthreads();
        #pragma unroll
        for (int j = 0; j < 4; ++j) {
            int ch = tid + 256 * j;
            int row = ch >> 3, off = (ch & 7) * 8;
            *(float4*)(&lsA[row * LP + off]) = ga[j];
        }
        nb = 0;
        for (int ch = tid; ch < Un * 8; ch += 256, ++nb) {
            int row = ch >> 3, off = (ch & 7) * 8;
            *(float4*)(&lsB[row * LP + off]) = gbv[nb];
        }
        __syncthreads();

        #pragma unroll
        for (int sub = 0; sub < 2; ++sub) {
            short8 af[2], bf[5];
            #pragma unroll
            for (int mf = 0; mf < 2; ++mf)
                af[mf] = *(const short8*)(&lsA[(mw + mf * 16 + lr) * LP + sub * 32 + kq * 8]);
            #pragma unroll
            for (int nf = 0; nf < 5; ++nf)
                bf[nf] = *(const short8*)(&lsB[(nf * 16 + lr) * LP + sub * 32 + kq * 8]);
            #pragma unroll
            for (int mf = 0; mf < 2; ++mf)
                #pragma unroll
                for (int nf = 0; nf < 5; ++nf)
                    acc[mf][nf] = __builtin_amdgcn_mfma_f32_16x16x32_bf16(
                        af[mf], bf[nf], acc[mf][nf], 0, 0, 0);
        }
    }

    #pragma unroll
    for (int mf = 0; mf < 2; ++mf)
        #pragma unroll
        for (int nf = 0; nf < 5; ++nf) {
            int u = nf * 16 + lr;
            float gb = gbias[b * Un + u];
            #pragma unroll
            for (int r = 0; r < 4; ++r) {
                int t = m0 + mw + mf * 16 + kq * 4 + r;
                glp[((size_t)(b * Tn + t)) * Un + u] = acc[mf][nf][r] + gb;
            }
        }
}

// ---------------- CTC forward recursion ----------------
__global__ __launch_bounds__(64) void ctc_fwd(
    const float* __restrict__ glp, const float* __restrict__ se,
    const int* __restrict__ ys, const int* __restrict__ hlens,
    const int* __restrict__ ylens, float* __restrict__ ll_out)
{
    const int b = blockIdx.x;
    const int l = threadIdx.x;

    int yl = ys[b * Ln + l];
    int ylm = (l >= 1) ? ys[b * Ln + l - 1] : -1;
    const bool allow1 = (l >= 1) && (yl != ylm);
    const int hl = hlens[b];

    const float* gb = glp + (size_t)b * Tn * Un;
    const float* seb = se + b * Tn;

    float lse0 = __logf(seb[0]);
    float a0 = (l == 0) ? (gb[0] - lse0) : NEG;
    float a1 = (l == 0) ? (gb[1] - lse0) : NEG;
    float a2 = NEG;

    // prefetch t=1
    float c0 = gb[Un], c1 = gb[Un + l + 1], sl = seb[1];

    for (int t = 1; t < Tn; ++t) {
        int tn = (t + 1 < Tn) ? (t + 1) : t;
        float p0 = gb[(size_t)tn * Un];
        float p1v = gb[(size_t)tn * Un + l + 1];
        float psl = seb[tn];

        float lse = __logf(sl);
        float lpb = c0 - lse;        // blank lp (all even states incl. s=128)
        float lpl = c1 - lse;        // label lp for s = 2l+1

        float p1 = __shfl_up(a1, 1, 64);
        if (l == 0) p1 = NEG;

        float u0 = lae2(a0, p1) + lpb;
        float u1 = lae3(a1, a0, allow1 ? p1 : NEG) + lpl;
        float u2 = lae2(a2, a1) + lpb;

        bool act = (t < hl);
        a0 = act ? u0 : a0;
        a1 = act ? u1 : a1;
        a2 = act ? u2 : a2;

        c0 = p0; c1 = p1v; sl = psl;
    }

    __shared__ float sh[132];
    sh[2 * l] = a0;
    sh[2 * l + 1] = a1;
    if (l == 63) sh[128] = a2;
    __syncthreads();

    if (l == 0) {
        int L = ylens[b];
        ll_out[b] = lae2(sh[2 * L], sh[2 * L - 1]);
    }
}

__global__ void finalize(const float* __restrict__ ll, float* __restrict__ out) {
    if (threadIdx.x == 0 && blockIdx.x == 0) {
        float s = 0.0f;
        #pragma unroll
        for (int b = 0; b < Bn; ++b) s += ll[b];
        out[0] = -s / (float)Bn;
    }
}

extern "C" void kernel_launch(void* const* d_in, const int* in_sizes, int n_in,
                              void* d_out, int out_size, void* d_ws, size_t ws_size,
                              hipStream_t stream) {
    const float* hs    = (const float*)d_in[0];
    const int*   hlens = (const int*)d_in[1];
    const int*   ys    = (const int*)d_in[2];
    const int*   ylens = (const int*)d_in[3];
    const float* W     = (const float*)d_in[4];
    const float* bias  = (const float*)d_in[5];
    float* out = (float*)d_out;

    char* ws = (char*)d_ws;
    unsigned short* hs_b = (unsigned short*)(ws);                       // 4,194,304 B
    unsigned short* w_b  = (unsigned short*)(ws + 4194304);             // 2,195,456 B
    unsigned short* wg_b = (unsigned short*)(ws + 6389760);             //   655,360 B
    float* glp   = (float*)(ws + 7045120);                              // 2,621,440 B
    float* se    = (float*)(ws + 9666560);                              //    32,768 B
    float* gbias = (float*)(ws + 9699328);                              //     5,120 B
    float* ll    = (float*)(ws + 9704448);                              //        64 B

    hipMemsetAsync(se, 0, Bn * Tn * sizeof(float), stream);
    conv<<<1024, 256, 0, stream>>>(hs, W, bias, ys, hs_b, w_b, wg_b, gbias);
    gemm_se<<<dim3(64, 67), 256, 0, stream>>>(hs_b, w_b, bias, se);
    gemm_gather<<<dim3(4, 16), 256, 0, stream>>>(hs_b, wg_b, gbias, glp);
    ctc_fwd<<<Bn, 64, 0, stream>>>(glp, se, ys, hlens, ylens, ll);
    finalize<<<1, 64, 0, stream>>>(ll, out);
}

// Round 3
// 346.947 us; speedup vs baseline: 3.6910x; 1.1964x over previous
//
#include <hip/hip_runtime.h>

#define NEG (-1e30f)

constexpr int Bn = 16;
constexpr int Tn = 512;
constexpr int Dn = 256;
constexpr int Vn = 4233;
constexpr int Vp = 4288;   // V padded to 67*64
constexpr int Ln = 64;     // LMAX
constexpr int Un = 80;     // padded gathered-label count (65 -> 80 = 5*16)
constexpr int LP = 72;     // LDS row stride in bf16 (64 + 8 pad)
constexpr int CS = 68;     // ctc LDS row stride in floats

typedef __attribute__((ext_vector_type(8))) short short8;
typedef __attribute__((ext_vector_type(4))) float f32x4;

__device__ __forceinline__ float lae2(float x, float y) {
    float m = fmaxf(x, y);
    return m + __logf(__expf(x - m) + __expf(y - m));
}
__device__ __forceinline__ float lae3(float x, float y, float z) {
    float m = fmaxf(fmaxf(x, y), z);
    return m + __logf(__expf(x - m) + __expf(y - m) + __expf(z - m));
}

__device__ __forceinline__ unsigned short cvt_bf16(float f) {
    unsigned int u = __float_as_uint(f);
    u = (u + 0x7fffu + ((u >> 16) & 1u)) >> 16;
    return (unsigned short)u;
}

// ---------------- conversion / gather prep ----------------
__global__ __launch_bounds__(256) void conv(
    const float* __restrict__ hs, const float* __restrict__ W,
    const float* __restrict__ bias, const int* __restrict__ ys,
    unsigned short* __restrict__ hs_b, unsigned short* __restrict__ w_b,
    unsigned short* __restrict__ wg_b, float* __restrict__ gbias)
{
    const int gid = blockIdx.x * 256 + threadIdx.x;
    const int stride = gridDim.x * 256;
    const float4* hs4 = (const float4*)hs;
    const float4* W4  = (const float4*)W;

    for (int i = gid; i < (Bn * Tn * Dn) / 4; i += stride) {
        float4 v = hs4[i];
        ushort4 o = make_ushort4(cvt_bf16(v.x), cvt_bf16(v.y), cvt_bf16(v.z), cvt_bf16(v.w));
        *(ushort4*)(&hs_b[i * 4]) = o;
    }
    for (int i = gid; i < Vp * (Dn / 4); i += stride) {
        int row = i >> 6;
        float4 v = make_float4(0.f, 0.f, 0.f, 0.f);
        if (row < Vn) v = W4[i];
        ushort4 o = make_ushort4(cvt_bf16(v.x), cvt_bf16(v.y), cvt_bf16(v.z), cvt_bf16(v.w));
        *(ushort4*)(&w_b[i * 4]) = o;
    }
    for (int i = gid; i < Bn * Un * (Dn / 4); i += stride) {
        int b = i / (Un * (Dn / 4));
        int rem = i - b * (Un * (Dn / 4));
        int u = rem >> 6;
        int k4 = rem & 63;
        int v = (u == 0) ? 0 : ((u <= Ln) ? ys[b * Ln + u - 1] : -1);
        float4 val = make_float4(0.f, 0.f, 0.f, 0.f);
        if (v >= 0) val = W4[(size_t)v * (Dn / 4) + k4];
        ushort4 o = make_ushort4(cvt_bf16(val.x), cvt_bf16(val.y), cvt_bf16(val.z), cvt_bf16(val.w));
        *(ushort4*)(&wg_b[i * 4]) = o;
    }
    for (int i = gid; i < Bn * Un; i += stride) {
        int b = i / Un;
        int u = i - b * Un;
        int v = (u == 0) ? 0 : ((u <= Ln) ? ys[b * Ln + u - 1] : -1);
        gbias[i] = (v >= 0) ? bias[v] : 0.0f;
    }
}

// ---------------- main GEMM: sum of exp over V ----------------
__global__ __launch_bounds__(256) void gemm_se(
    const unsigned short* __restrict__ hs_b, const unsigned short* __restrict__ w_b,
    const float* __restrict__ bias, float* __restrict__ se)
{
    __shared__ short lsA[128 * LP];
    __shared__ short lsB[64 * LP];

    const int tid = threadIdx.x;
    const int lane = tid & 63;
    const int w = tid >> 6;
    const int lr = lane & 15;
    const int kq = lane >> 4;
    const int m0 = blockIdx.x * 128;
    const int n0 = blockIdx.y * 64;
    const int mw = w * 32;

    f32x4 acc[2][4];
    #pragma unroll
    for (int mf = 0; mf < 2; ++mf)
        #pragma unroll
        for (int nf = 0; nf < 4; ++nf)
            acc[mf][nf] = (f32x4){0.f, 0.f, 0.f, 0.f};

    for (int ks = 0; ks < 4; ++ks) {
        const int k0 = ks * 64;
        float4 ga[4], gb2[2];
        #pragma unroll
        for (int j = 0; j < 4; ++j) {
            int ch = tid + 256 * j;
            int row = ch >> 3, off = (ch & 7) * 8;
            ga[j] = *(const float4*)(hs_b + (size_t)(m0 + row) * Dn + k0 + off);
        }
        #pragma unroll
        for (int j = 0; j < 2; ++j) {
            int ch = tid + 256 * j;
            int row = ch >> 3, off = (ch & 7) * 8;
            gb2[j] = *(const float4*)(w_b + (size_t)(n0 + row) * Dn + k0 + off);
        }
        __syncthreads();
        #pragma unroll
        for (int j = 0; j < 4; ++j) {
            int ch = tid + 256 * j;
            int row = ch >> 3, off = (ch & 7) * 8;
            *(float4*)(&lsA[row * LP + off]) = ga[j];
        }
        #pragma unroll
        for (int j = 0; j < 2; ++j) {
            int ch = tid + 256 * j;
            int row = ch >> 3, off = (ch & 7) * 8;
            *(float4*)(&lsB[row * LP + off]) = gb2[j];
        }
        __syncthreads();

        #pragma unroll
        for (int sub = 0; sub < 2; ++sub) {
            short8 af[2], bf[4];
            #pragma unroll
            for (int mf = 0; mf < 2; ++mf)
                af[mf] = *(const short8*)(&lsA[(mw + mf * 16 + lr) * LP + sub * 32 + kq * 8]);
            #pragma unroll
            for (int nf = 0; nf < 4; ++nf)
                bf[nf] = *(const short8*)(&lsB[(nf * 16 + lr) * LP + sub * 32 + kq * 8]);
            #pragma unroll
            for (int mf = 0; mf < 2; ++mf)
                #pragma unroll
                for (int nf = 0; nf < 4; ++nf)
                    acc[mf][nf] = __builtin_amdgcn_mfma_f32_16x16x32_bf16(
                        af[mf], bf[nf], acc[mf][nf], 0, 0, 0);
        }
    }

    float bcol[4]; bool valid[4];
    #pragma unroll
    for (int nf = 0; nf < 4; ++nf) {
        int col = n0 + nf * 16 + lr;
        valid[nf] = (col < Vn);
        bcol[nf] = valid[nf] ? bias[col] : 0.0f;
    }
    #pragma unroll
    for (int mf = 0; mf < 2; ++mf) {
        #pragma unroll
        for (int r = 0; r < 4; ++r) {
            float s = 0.0f;
            #pragma unroll
            for (int nf = 0; nf < 4; ++nf)
                if (valid[nf]) s += __expf(acc[mf][nf][r] + bcol[nf]);
            #pragma unroll
            for (int off = 1; off < 16; off <<= 1) s += __shfl_xor(s, off, 64);
            if (lr == 0)
                atomicAdd(&se[m0 + mw + mf * 16 + kq * 4 + r], s);
        }
    }
}

// ---------------- gathered-label GEMM -> normalized log-probs ----------------
// glp[b][t][u] = logit(ext label u) + bias - log(sum exp) ; requires se ready.
__global__ __launch_bounds__(256) void gemm_gather(
    const unsigned short* __restrict__ hs_b, const unsigned short* __restrict__ wg_b,
    const float* __restrict__ gbias, const float* __restrict__ se,
    float* __restrict__ glp)
{
    __shared__ short lsA[128 * LP];
    __shared__ short lsB[Un * LP];

    const int tid = threadIdx.x;
    const int lane = tid & 63;
    const int w = tid >> 6;
    const int lr = lane & 15;
    const int kq = lane >> 4;
    const int m0 = blockIdx.x * 128;
    const int b = blockIdx.y;
    const int mw = w * 32;

    f32x4 acc[2][5];
    #pragma unroll
    for (int mf = 0; mf < 2; ++mf)
        #pragma unroll
        for (int nf = 0; nf < 5; ++nf)
            acc[mf][nf] = (f32x4){0.f, 0.f, 0.f, 0.f};

    for (int ks = 0; ks < 4; ++ks) {
        const int k0 = ks * 64;
        float4 ga[4];
        #pragma unroll
        for (int j = 0; j < 4; ++j) {
            int ch = tid + 256 * j;
            int row = ch >> 3, off = (ch & 7) * 8;
            ga[j] = *(const float4*)(hs_b + (size_t)(b * Tn + m0 + row) * Dn + k0 + off);
        }
        float4 gbv[3];
        int nb = 0;
        for (int ch = tid; ch < Un * 8; ch += 256, ++nb) {
            int row = ch >> 3, off = (ch & 7) * 8;
            gbv[nb] = *(const float4*)(wg_b + (size_t)(b * Un + row) * Dn + k0 + off);
        }
        __syncthreads();
        #pragma unroll
        for (int j = 0; j < 4; ++j) {
            int ch = tid + 256 * j;
            int row = ch >> 3, off = (ch & 7) * 8;
            *(float4*)(&lsA[row * LP + off]) = ga[j];
        }
        nb = 0;
        for (int ch = tid; ch < Un * 8; ch += 256, ++nb) {
            int row = ch >> 3, off = (ch & 7) * 8;
            *(float4*)(&lsB[row * LP + off]) = gbv[nb];
        }
        __syncthreads();

        #pragma unroll
        for (int sub = 0; sub < 2; ++sub) {
            short8 af[2], bf[5];
            #pragma unroll
            for (int mf = 0; mf < 2; ++mf)
                af[mf] = *(const short8*)(&lsA[(mw + mf * 16 + lr) * LP + sub * 32 + kq * 8]);
            #pragma unroll
            for (int nf = 0; nf < 5; ++nf)
                bf[nf] = *(const short8*)(&lsB[(nf * 16 + lr) * LP + sub * 32 + kq * 8]);
            #pragma unroll
            for (int mf = 0; mf < 2; ++mf)
                #pragma unroll
                for (int nf = 0; nf < 5; ++nf)
                    acc[mf][nf] = __builtin_amdgcn_mfma_f32_16x16x32_bf16(
                        af[mf], bf[nf], acc[mf][nf], 0, 0, 0);
        }
    }

    #pragma unroll
    for (int mf = 0; mf < 2; ++mf) {
        #pragma unroll
        for (int r = 0; r < 4; ++r) {
            int t = m0 + mw + mf * 16 + kq * 4 + r;
            float lse = __logf(se[b * Tn + t]);
            #pragma unroll
            for (int nf = 0; nf < 5; ++nf) {
                int u = nf * 16 + lr;
                glp[((size_t)(b * Tn + t)) * Un + u] =
                    acc[mf][nf][r] + gbias[b * Un + u] - lse;
            }
        }
    }
}

// ---------------- CTC forward recursion ----------------
// 256 threads: chunked double-buffered LDS staging of lp (64 timesteps/chunk);
// all 4 waves run the recursion redundantly (lanes hold alpha[2l], alpha[2l+1]).
__global__ __launch_bounds__(256) void ctc_fwd(
    const float* __restrict__ glp, const int* __restrict__ ys,
    const int* __restrict__ hlens, const int* __restrict__ ylens,
    float* __restrict__ ll_out)
{
    __shared__ float ls[2][64 * CS + 4];
    __shared__ float sh[132];

    const int b = blockIdx.x;
    const int tid = threadIdx.x;
    const int l = tid & 63;

    int yl = ys[b * Ln + l];
    int ylm = (l >= 1) ? ys[b * Ln + l - 1] : -1;
    const bool allow1 = (l >= 1) && (yl != ylm);
    const int hl = hlens[b];

    const float* gb = glp + (size_t)b * Tn * Un;

    // ---- stage chunk 0 directly ----
    {
        const float* src = gb;
        #pragma unroll
        for (int j = 0; j < 4; ++j) {
            int i = tid + j * 256;
            int tt = i >> 4, u4 = (i & 15) * 4;
            *(float4*)(&ls[0][tt * CS + u4]) = *(const float4*)(src + tt * 80 + u4);
        }
        if (tid < 64) ls[0][tid * CS + 64] = src[tid * 80 + 64];
    }
    __syncthreads();

    float a0 = (l == 0) ? ls[0][0] : NEG;
    float a1 = (l == 0) ? ls[0][1] : NEG;
    float a2 = NEG;

    float4 r4[4];
    float r1 = 0.0f;

    for (int c = 0; c < 8; ++c) {
        // issue next chunk's global loads into registers (latency hidden by compute)
        if (c < 7) {
            const float* src = gb + (size_t)(c + 1) * 64 * 80;
            #pragma unroll
            for (int j = 0; j < 4; ++j) {
                int i = tid + j * 256;
                int tt = i >> 4, u4 = (i & 15) * 4;
                r4[j] = *(const float4*)(src + tt * 80 + u4);
            }
            if (tid < 64) r1 = src[tid * 80 + 64];
        }

        const float* buf = ls[c & 1];
        const int tstart = (c == 0) ? 1 : 0;
        const int tbase = c * 64;
        for (int tt = tstart; tt < 64; ++tt) {
            float lpb = buf[tt * CS];
            float lpl = buf[tt * CS + 1 + l];

            float p1 = __shfl_up(a1, 1, 64);
            if (l == 0) p1 = NEG;

            float u0 = lae2(a0, p1) + lpb;
            float u1 = lae3(a1, a0, allow1 ? p1 : NEG) + lpl;
            float u2 = lae2(a2, a1) + lpb;

            bool act = (tbase + tt) < hl;
            a0 = act ? u0 : a0;
            a1 = act ? u1 : a1;
            a2 = act ? u2 : a2;
        }

        if (c < 7) {
            float* dst = ls[(c + 1) & 1];
            #pragma unroll
            for (int j = 0; j < 4; ++j) {
                int i = tid + j * 256;
                int tt = i >> 4, u4 = (i & 15) * 4;
                *(float4*)(&dst[tt * CS + u4]) = r4[j];
            }
            if (tid < 64) dst[tid * CS + 64] = r1;
        }
        __syncthreads();
    }

    if (tid < 64) {
        sh[2 * l] = a0;
        sh[2 * l + 1] = a1;
        if (l == 63) sh[128] = a2;
    }
    __syncthreads();

    if (tid == 0) {
        int L = ylens[b];
        ll_out[b] = lae2(sh[2 * L], sh[2 * L - 1]);
    }
}

__global__ void finalize(const float* __restrict__ ll, float* __restrict__ out) {
    if (threadIdx.x == 0 && blockIdx.x == 0) {
        float s = 0.0f;
        #pragma unroll
        for (int b = 0; b < Bn; ++b) s += ll[b];
        out[0] = -s / (float)Bn;
    }
}

extern "C" void kernel_launch(void* const* d_in, const int* in_sizes, int n_in,
                              void* d_out, int out_size, void* d_ws, size_t ws_size,
                              hipStream_t stream) {
    const float* hs    = (const float*)d_in[0];
    const int*   hlens = (const int*)d_in[1];
    const int*   ys    = (const int*)d_in[2];
    const int*   ylens = (const int*)d_in[3];
    const float* W     = (const float*)d_in[4];
    const float* bias  = (const float*)d_in[5];
    float* out = (float*)d_out;

    char* ws = (char*)d_ws;
    unsigned short* hs_b = (unsigned short*)(ws);                       // 4,194,304 B
    unsigned short* w_b  = (unsigned short*)(ws + 4194304);             // 2,195,456 B
    unsigned short* wg_b = (unsigned short*)(ws + 6389760);             //   655,360 B
    float* glp   = (float*)(ws + 7045120);                              // 2,621,440 B
    float* se    = (float*)(ws + 9666560);                              //    32,768 B
    float* gbias = (float*)(ws + 9699328);                              //     5,120 B
    float* ll    = (float*)(ws + 9704448);                              //        64 B

    hipMemsetAsync(se, 0, Bn * Tn * sizeof(float), stream);
    conv<<<1024, 256, 0, stream>>>(hs, W, bias, ys, hs_b, w_b, wg_b, gbias);
    gemm_se<<<dim3(64, 67), 256, 0, stream>>>(hs_b, w_b, bias, se);
    gemm_gather<<<dim3(4, 16), 256, 0, stream>>>(hs_b, wg_b, gbias, se, glp);
    ctc_fwd<<<Bn, 256, 0, stream>>>(glp, ys, hlens, ylens, ll);
    finalize<<<1, 64, 0, stream>>>(ll, out);
}